// Round 6
// baseline (254.909 us; speedup 1.0000x reference)
//
#include <hip/hip_runtime.h>
#include <stdint.h>

#define NND 4096
#define DIM 1024      // D = GC1 = GC2
#define FC1N 512

typedef __attribute__((ext_vector_type(8))) short short8;
typedef __attribute__((ext_vector_type(4))) float floatx4;
typedef unsigned short u16;
typedef unsigned int u32;

__device__ __forceinline__ u16 f2bf(float f) {
    union { float f; u32 u; } a; a.f = f;
    u32 u = a.u;
    return (u16)((u + 0x7fffu + ((u >> 16) & 1u)) >> 16);   // RNE
}
__device__ __forceinline__ float bf2f(u16 h) {
    union { u32 u; float f; } a; a.u = ((u32)h) << 16; return a.f;
}
__device__ __forceinline__ float selu_f(float x) {
    const float lam = 1.0507009873554805f;
    const float alp = 1.6732632423543772f;
    return x > 0.f ? lam * x : lam * alp * (expf(x) - 1.f);
}

// ---- prep: cvt x->bf16 (blocks 0..511), transpose W1/W2 (512..1023), zero ---
__global__ void k_prep(const float* __restrict__ x, const float* __restrict__ w1,
                       const float* __restrict__ w2, u16* __restrict__ Xb,
                       u16* __restrict__ W1t, u16* __restrict__ W2t,
                       float* __restrict__ zero_base) {
    int b = blockIdx.x, t = threadIdx.x;
    if (b < 512) {
        const float4* xin = (const float4*)x;
        ushort4* xo = (ushort4*)Xb;
        int base = b * 2048 + t;
        #pragma unroll
        for (int i = 0; i < 8; ++i) {
            float4 v = xin[base + i * 256];
            ushort4 o; o.x = f2bf(v.x); o.y = f2bf(v.y); o.z = f2bf(v.z); o.w = f2bf(v.w);
            xo[base + i * 256] = o;
        }
        if (b == 0)
            for (int i = t; i < 1544; i += 256) zero_base[i] = 0.f;  // pooled+zacc+cnts
        return;
    }
    // transpose [K][N] fp32 -> [N][K] bf16, 64x64 tiles
    int job = b - 512;
    const float* in = (job & 256) ? w2 : w1;
    u16* out = (job & 256) ? W2t : W1t;
    int tl = job & 255;
    int r0 = (tl >> 4) * 64, c0 = (tl & 15) * 64;
    __shared__ float tile[64][65];
    int cg = t & 15, rb = t >> 4;
    #pragma unroll
    for (int rr = 0; rr < 4; ++rr) {
        int row = rb + rr * 16;
        float4 v = *(const float4*)(in + (size_t)(r0 + row) * DIM + c0 + cg * 4);
        tile[row][cg * 4 + 0] = v.x; tile[row][cg * 4 + 1] = v.y;
        tile[row][cg * 4 + 2] = v.z; tile[row][cg * 4 + 3] = v.w;
    }
    __syncthreads();
    #pragma unroll
    for (int rr = 0; rr < 4; ++rr) {
        int nl = rb + rr * 16;
        int kl = cg * 4;
        ushort4 o;
        o.x = f2bf(tile[kl + 0][nl]); o.y = f2bf(tile[kl + 1][nl]);
        o.z = f2bf(tile[kl + 2][nl]); o.w = f2bf(tile[kl + 3][nl]);
        *(ushort4*)(out + (size_t)(c0 + nl) * DIM + r0 + kl) = o;
    }
}

// ---- fused GEMM + band-stencil + SELU (+ FC head in mode 1) -----------------
// Block: 128 threads = 2 waves. Output rows m0..m0+63, cols n0..n0+63.
// Internal rows m0-16..m0+79 (96; +-8 halo, edges clamped & zeroed via sdinv=0).
// Wave w: internal rows w*48..w*48+47 (mt=3) x all 64 cols (nt=4).
// NO LDS / NO barriers in K-loop: A- and B-fragments loaded dwordx4 direct from
// global (L2-hot; same-A blocks share an XCD since grid y-stride 64 % 8 == 0).
// LDS only holds the 96x66 bf16 Y tile for the band-stencil epilogue.
// Grid 64x16 = 1024 blocks = 8 blocks/CU = 16 waves/CU.
__launch_bounds__(128, 4)
__global__ void k_gemmband(const u16* __restrict__ A, const u16* __restrict__ Bt,
                           const float* __restrict__ bias,
                           const float* __restrict__ fw, const float* __restrict__ bw,
                           u16* __restrict__ H, float* __restrict__ pooled,
                           const float* __restrict__ fcw1, const float* __restrict__ fcb1,
                           const float* __restrict__ fcw2, const float* __restrict__ fcb2,
                           float* __restrict__ zacc, u32* __restrict__ cnt,
                           float* __restrict__ out, int mode) {
    __shared__ __align__(16) u16 Yt[96][66];     // 12.7 KB
    __shared__ float sdinv_s[96];
    __shared__ float wt_s[17];
    __shared__ float pl[2][64];
    __shared__ u32 ticket_s;

    const int m0 = blockIdx.x * 64, n0 = blockIdx.y * 64;
    const int t = threadIdx.x, wave = t >> 6, lane = t & 63;
    const int q = lane >> 4, r = lane & 15;

    if (t < 96) {                                // sdinv for internal rows
        int g = m0 - 16 + t;
        float s = 0.f;
        if (g >= 0 && g < NND) {
            float deg = 1.f;
            #pragma unroll
            for (int j = 0; j < 8; ++j) {
                if (g + j + 1 < NND) deg += fw[j];
                if (g - j - 1 >= 0)  deg += bw[j];
            }
            s = 1.f / sqrtf(deg);
        }
        sdinv_s[t] = s;
    } else if (t < 113) {
        int o = t - 104;                         // -8..8
        wt_s[t - 96] = (o == 0) ? 1.f : (o > 0 ? fw[o - 1] : bw[-o - 1]);
    }

    const u16* aptr[3];
    #pragma unroll
    for (int mt = 0; mt < 3; ++mt) {
        int g = m0 - 16 + wave * 48 + mt * 16 + r;
        g = g < 0 ? 0 : (g > NND - 1 ? NND - 1 : g);   // clamp; zeroed by sdinv
        aptr[mt] = A + (size_t)g * DIM + q * 8;
    }
    const u16* bptr[4];
    #pragma unroll
    for (int nt = 0; nt < 4; ++nt)
        bptr[nt] = Bt + (size_t)(n0 + nt * 16 + r) * DIM + q * 8;

    floatx4 acc[3][4];
    #pragma unroll
    for (int mt = 0; mt < 3; ++mt)
        #pragma unroll
        for (int nt = 0; nt < 4; ++nt) acc[mt][nt] = (floatx4)0.f;

    #pragma unroll 4
    for (int k0 = 0; k0 < DIM; k0 += 32) {       // barrier-free K-loop
        short8 bfr[4], afr[3];
        #pragma unroll
        for (int nt = 0; nt < 4; ++nt) bfr[nt] = *(const short8*)(bptr[nt] + k0);
        #pragma unroll
        for (int mt = 0; mt < 3; ++mt) afr[mt] = *(const short8*)(aptr[mt] + k0);
        #pragma unroll
        for (int mt = 0; mt < 3; ++mt)
            #pragma unroll
            for (int nt = 0; nt < 4; ++nt)
                acc[mt][nt] = __builtin_amdgcn_mfma_f32_16x16x32_bf16(afr[mt], bfr[nt], acc[mt][nt], 0, 0, 0);
    }

    // epilogue: bias + Y tile (bf16) into LDS
    #pragma unroll
    for (int nt = 0; nt < 4; ++nt) {
        int col = nt * 16 + r;
        float bv = bias[n0 + col];
        #pragma unroll
        for (int mt = 0; mt < 3; ++mt)
            #pragma unroll
            for (int rr = 0; rr < 4; ++rr)       // C/D: col=lane&15, row=q*4+reg
                Yt[wave * 48 + mt * 16 + q * 4 + rr][col] = f2bf(acc[mt][nt][rr] + bv);
    }
    __syncthreads();

    // band stencil: each thread 32 output rows x 1 col; rotating 17-tap window
    int col = t & 63;
    int r0w = wave * 32;
    float w[17];
    #pragma unroll
    for (int o = 0; o < 17; ++o) w[o] = wt_s[o];
    float win[17];
    #pragma unroll
    for (int j = 0; j < 16; ++j) {
        int T = r0w + 8 + j;
        win[j] = sdinv_s[T] * bf2f(Yt[T][col]);
    }
    float psum = 0.f;
    #pragma unroll
    for (int rr = 0; rr < 32; ++rr) {
        int T = r0w + 24 + rr;
        win[(rr + 16) % 17] = sdinv_s[T] * bf2f(Yt[T][col]);
        float a = 0.f;
        #pragma unroll
        for (int o = 0; o < 17; ++o) a += w[o] * win[(rr + o) % 17];
        float v = selu_f(a * sdinv_s[r0w + 16 + rr]);
        if (mode == 0) H[(size_t)(m0 + r0w + rr) * DIM + n0 + col] = f2bf(v);
        else psum += v;
    }
    if (mode == 0) return;

    // ---- mode 1: mean-pool + fused FC head ----------------------------------
    pl[wave][col] = psum;
    __syncthreads();
    if (t < 64) atomicAdd(&pooled[n0 + t], pl[0][t] + pl[1][t]);
    __threadfence();
    __syncthreads();
    if (t == 0) ticket_s = atomicAdd(&cnt[0], 1u);
    __syncthreads();
    u32 ticket = ticket_s;
    if (ticket < 1024 - 16) return;              // 16 elected blocks run the FC head
    if (t == 0) {
        while (__hip_atomic_load(&cnt[0], __ATOMIC_ACQUIRE, __HIP_MEMORY_SCOPE_AGENT) < 1024u)
            __builtin_amdgcn_s_sleep(2);
    }
    __syncthreads();
    __threadfence();
    // fc1: k-slice of 64 pooled rows -> 512 outputs (4 per thread)
    int kb = (int)(ticket - (1024 - 16)) * 64;
    if (t < 64)
        pl[0][t] = __hip_atomic_load(&pooled[kb + t], __ATOMIC_RELAXED,
                                     __HIP_MEMORY_SCOPE_AGENT) * (1.f / NND);
    __syncthreads();
    float a0 = 0.f, a1 = 0.f, a2 = 0.f, a3 = 0.f;
    #pragma unroll 8
    for (int kk = 0; kk < 64; ++kk) {
        float pv = pl[0][kk];
        const float* wrow = fcw1 + (size_t)(kb + kk) * FC1N + t;
        a0 += pv * wrow[0];   a1 += pv * wrow[128];
        a2 += pv * wrow[256]; a3 += pv * wrow[384];
    }
    atomicAdd(&zacc[t], a0);       atomicAdd(&zacc[t + 128], a1);
    atomicAdd(&zacc[t + 256], a2); atomicAdd(&zacc[t + 384], a3);
    __threadfence();
    __syncthreads();
    if (t == 0) ticket_s = atomicAdd(&cnt[1], 1u);
    __syncthreads();
    if (ticket_s != 15) return;                  // only the last fc1 block continues
    __threadfence();
    float r0p = 0.f, r1p = 0.f;
    #pragma unroll
    for (int i = 0; i < 4; ++i) {
        int o = t + i * 128;
        float zv = __hip_atomic_load(&zacc[o], __ATOMIC_RELAXED, __HIP_MEMORY_SCOPE_AGENT);
        float z = selu_f(zv + fcb1[o]);
        r0p += z * fcw2[o * 2 + 0];
        r1p += z * fcw2[o * 2 + 1];
    }
    float* red = (float*)&Yt[0][0];
    red[t] = r0p; red[128 + t] = r1p;
    __syncthreads();
    #pragma unroll 1
    for (int s2 = 64; s2 > 0; s2 >>= 1) {
        if (t < s2) { red[t] += red[t + s2]; red[128 + t] += red[128 + t + s2]; }
        __syncthreads();
    }
    if (t == 0) { out[0] = red[0] + fcb2[0]; out[1] = red[1] + fcb2[1]; }
}

extern "C" void kernel_launch(void* const* d_in, const int* in_sizes, int n_in,
                              void* d_out, int out_size, void* d_ws, size_t ws_size,
                              hipStream_t stream) {
    const float* x     = (const float*)d_in[0];
    const float* fw    = (const float*)d_in[1];
    const float* bw    = (const float*)d_in[2];
    const float* gc_w1 = (const float*)d_in[3];
    const float* gc_b1 = (const float*)d_in[4];
    const float* gc_w2 = (const float*)d_in[5];
    const float* gc_b2 = (const float*)d_in[6];
    const float* fc_w1 = (const float*)d_in[7];
    const float* fc_b1 = (const float*)d_in[8];
    const float* fc_w2 = (const float*)d_in[9];
    const float* fc_b2 = (const float*)d_in[10];
    float* out = (float*)d_out;

    char* ws = (char*)d_ws;
    u16*   Xb     = (u16*)(ws);                       // 8 MB
    u16*   H1     = (u16*)(ws + (8u  << 20));         // 8 MB
    u16*   W1t    = (u16*)(ws + (16u << 20));         // 2 MB
    u16*   W2t    = (u16*)(ws + (18u << 20));         // 2 MB
    float* pooled = (float*)(ws + (20u << 20));       // 1024 f
    float* zacc   = pooled + 1024;                    // 512 f
    u32*   cnt    = (u32*)(zacc + 512);               // 2 u32 (zeroed in prep)

    k_prep<<<1024, 256, 0, stream>>>(x, gc_w1, gc_w2, Xb, W1t, W2t, pooled);
    k_gemmband<<<dim3(64, 16), 128, 0, stream>>>(Xb, W1t, gc_b1, fw, bw, H1, nullptr,
                                                 nullptr, nullptr, nullptr, nullptr,
                                                 nullptr, nullptr, nullptr, 0);
    k_gemmband<<<dim3(64, 16), 128, 0, stream>>>(H1, W2t, gc_b2, fw, bw, nullptr, pooled,
                                                 fc_w1, fc_b1, fc_w2, fc_b2,
                                                 zacc, cnt, out, 1);
}

// Round 7
// 181.327 us; speedup vs baseline: 1.4058x; 1.4058x over previous
//
#include <hip/hip_runtime.h>
#include <stdint.h>

#define NND 4096
#define DIM 1024      // D = GC1 = GC2
#define FC1N 512

typedef __attribute__((ext_vector_type(8))) short short8;
typedef __attribute__((ext_vector_type(4))) float floatx4;
typedef unsigned short u16;
typedef unsigned int u32;

__device__ __forceinline__ u16 f2bf(float f) {
    union { float f; u32 u; } a; a.f = f;
    u32 u = a.u;
    return (u16)((u + 0x7fffu + ((u >> 16) & 1u)) >> 16);   // RNE
}
__device__ __forceinline__ float bf2f(u16 h) {
    union { u32 u; float f; } a; a.u = ((u32)h) << 16; return a.f;
}
__device__ __forceinline__ float selu_f(float x) {
    const float lam = 1.0507009873554805f;
    const float alp = 1.6732632423543772f;
    return x > 0.f ? lam * x : lam * alp * (expf(x) - 1.f);
}
__device__ __forceinline__ void async16(const u16* g, u16* l) {
    __builtin_amdgcn_global_load_lds((const __attribute__((address_space(1))) u32*)g,
                                     (__attribute__((address_space(3))) u32*)l, 16, 0, 0);
}

// ---- prep: cvt x->bf16 (blocks 0..511), transpose W1/W2 (512..1023), zero ---
__global__ void k_prep(const float* __restrict__ x, const float* __restrict__ w1,
                       const float* __restrict__ w2, u16* __restrict__ Xb,
                       u16* __restrict__ W1t, u16* __restrict__ W2t,
                       float* __restrict__ zero_base) {
    int b = blockIdx.x, t = threadIdx.x;
    if (b < 512) {
        const float4* xin = (const float4*)x;
        ushort4* xo = (ushort4*)Xb;
        int base = b * 2048 + t;
        #pragma unroll
        for (int i = 0; i < 8; ++i) {
            float4 v = xin[base + i * 256];
            ushort4 o; o.x = f2bf(v.x); o.y = f2bf(v.y); o.z = f2bf(v.z); o.w = f2bf(v.w);
            xo[base + i * 256] = o;
        }
        if (b == 0)
            for (int i = t; i < 1544; i += 256) zero_base[i] = 0.f;  // pooled+zacc+cnts
        return;
    }
    // transpose [K][N] fp32 -> [N][K] bf16, 64x64 tiles
    int job = b - 512;
    const float* in = (job & 256) ? w2 : w1;
    u16* out = (job & 256) ? W2t : W1t;
    int tl = job & 255;
    int r0 = (tl >> 4) * 64, c0 = (tl & 15) * 64;
    __shared__ float tile[64][65];
    int cg = t & 15, rb = t >> 4;
    #pragma unroll
    for (int rr = 0; rr < 4; ++rr) {
        int row = rb + rr * 16;
        float4 v = *(const float4*)(in + (size_t)(r0 + row) * DIM + c0 + cg * 4);
        tile[row][cg * 4 + 0] = v.x; tile[row][cg * 4 + 1] = v.y;
        tile[row][cg * 4 + 2] = v.z; tile[row][cg * 4 + 3] = v.w;
    }
    __syncthreads();
    #pragma unroll
    for (int rr = 0; rr < 4; ++rr) {
        int nl = rb + rr * 16;
        int kl = cg * 4;
        ushort4 o;
        o.x = f2bf(tile[kl + 0][nl]); o.y = f2bf(tile[kl + 1][nl]);
        o.z = f2bf(tile[kl + 2][nl]); o.w = f2bf(tile[kl + 3][nl]);
        *(ushort4*)(out + (size_t)(c0 + nl) * DIM + r0 + kl) = o;
    }
}

// ---- fused GEMM + band-stencil + SELU (+ FC head in mode 1) -----------------
// Block: 256 threads = 4 waves (2M x 2N). Output rows m0..m0+63, cols n0..n0+127.
// Internal rows m0-16..m0+79 (96; +-8 halo, edges clamped & zeroed via sdinv=0).
// Wave tile 48x64 (acc 3x4). BK=64 double-buffered global_load_lds w16, XOR
// seg swizzle, 1 barrier/iter. Grid 64x8 = 512 blocks = 2 blocks/CU.
// mode 0: write H bf16. mode 1: mean-pool + fused FC head via block election.
__launch_bounds__(256, 2)
__global__ void k_gemmband(const u16* __restrict__ A, const u16* __restrict__ Bt,
                           const float* __restrict__ bias,
                           const float* __restrict__ fw, const float* __restrict__ bw,
                           u16* __restrict__ H, float* __restrict__ pooled,
                           const float* __restrict__ fcw1, const float* __restrict__ fcb1,
                           const float* __restrict__ fcw2, const float* __restrict__ fcb2,
                           float* __restrict__ zacc, u32* __restrict__ cnt,
                           float* __restrict__ out, int mode) {
    __shared__ __align__(16) u16 stage[2][14336]; // per buf: A 12 chunks | B 16 chunks (28 KB)
    __shared__ float sdinv_s[96];
    __shared__ float wt_s[17];
    __shared__ float pl[2][128];
    __shared__ u32 ticket_s;

    const int m0 = blockIdx.x * 64, n0 = blockIdx.y * 128;
    const int t = threadIdx.x, wave = t >> 6, lane = t & 63;
    const int q = lane >> 4, r = lane & 15;
    const int wm = wave & 1, wn = wave >> 1;
    const int Lrow = lane >> 3, Lseg = lane & 7;

    if (t < 96) {                                 // sdinv for internal rows
        int g = m0 - 16 + t;
        float s = 0.f;
        if (g >= 0 && g < NND) {
            float deg = 1.f;
            #pragma unroll
            for (int j = 0; j < 8; ++j) {
                if (g + j + 1 < NND) deg += fw[j];
                if (g - j - 1 >= 0)  deg += bw[j];
            }
            s = 1.f / sqrtf(deg);
        }
        sdinv_s[t] = s;
    } else if (t >= 128 && t < 145) {
        int o = t - 136;                          // -8..8
        wt_s[t - 128] = (o == 0) ? 1.f : (o > 0 ? fw[o - 1] : bw[-o - 1]);
    }

    floatx4 acc[3][4];
    #pragma unroll
    for (int mt = 0; mt < 3; ++mt)
        #pragma unroll
        for (int nt = 0; nt < 4; ++nt) acc[mt][nt] = (floatx4)0.f;

    auto issue = [&](int buf, int kb) {
        #pragma unroll
        for (int i = 0; i < 7; ++i) {             // 28 chunks: 12 A (96 rows) + 16 B (128)
            int c = wave * 7 + i;
            u16* dst = &stage[buf][c * 512];      // wave-uniform base + lane*16B
            const u16* src;
            if (c < 12) {
                int row = c * 8 + Lrow;           // internal A row 0..95
                int g = m0 - 16 + row;
                g = g < 0 ? 0 : (g > NND - 1 ? NND - 1 : g);  // clamp; zeroed by sdinv
                src = A + (size_t)g * DIM + kb + ((Lseg ^ Lrow) * 8);
            } else {
                int row = (c - 12) * 8 + Lrow;    // B row 0..127
                src = Bt + (size_t)(n0 + row) * DIM + kb + ((Lseg ^ Lrow) * 8);
            }
            async16(src, dst);
        }
    };

    issue(0, 0);
    #pragma unroll 1
    for (int k = 0; k < 16; ++k) {
        __syncthreads();                          // cur-buf staged + prev compute drained
        if (k < 15) issue((k + 1) & 1, (k + 1) * 64);
        const u16* As = &stage[k & 1][0];
        const u16* Bs = &stage[k & 1][6144];
        #pragma unroll
        for (int s = 0; s < 2; ++s) {             // two K=32 sub-steps
            int j0 = s * 4 + q;
            short8 bfr[4];
            #pragma unroll
            for (int nt = 0; nt < 4; ++nt) {
                int nl = wn * 64 + nt * 16 + r;
                bfr[nt] = *(const short8*)&Bs[nl * 64 + ((j0 ^ (nl & 7)) * 8)];
            }
            #pragma unroll
            for (int mt = 0; mt < 3; ++mt) {
                int ml = wm * 48 + mt * 16 + r;
                short8 afr = *(const short8*)&As[ml * 64 + ((j0 ^ (ml & 7)) * 8)];
                #pragma unroll
                for (int nt = 0; nt < 4; ++nt)
                    acc[mt][nt] = __builtin_amdgcn_mfma_f32_16x16x32_bf16(afr, bfr[nt], acc[mt][nt], 0, 0, 0);
            }
        }
    }
    // epilogue: bias + Y tile (bf16) into LDS over stage[0] (96x130x2 = 25 KB)
    u16 (*Yt)[130] = (u16(*)[130])&stage[0][0];
    #pragma unroll
    for (int nt = 0; nt < 4; ++nt) {
        int col = wn * 64 + nt * 16 + r;
        float bv = bias[n0 + col];
        #pragma unroll
        for (int mt = 0; mt < 3; ++mt)
            #pragma unroll
            for (int rr = 0; rr < 4; ++rr)        // C/D: col=lane&15, row=q*4+reg
                Yt[wm * 48 + mt * 16 + q * 4 + rr][col] = f2bf(acc[mt][nt][rr] + bv);
    }
    __syncthreads();

    // band stencil: each thread 32 output rows x 1 col; rotating 17-tap window
    int col = t & 127;
    int r0w = (t >> 7) * 32;
    float w[17];
    #pragma unroll
    for (int o = 0; o < 17; ++o) w[o] = wt_s[o];
    float win[17];
    #pragma unroll
    for (int j = 0; j < 16; ++j) {
        int T = r0w + 8 + j;
        win[j] = sdinv_s[T] * bf2f(Yt[T][col]);
    }
    float psum = 0.f;
    #pragma unroll
    for (int rr = 0; rr < 32; ++rr) {
        int T = r0w + 24 + rr;
        win[(rr + 16) % 17] = sdinv_s[T] * bf2f(Yt[T][col]);
        float a = 0.f;
        #pragma unroll
        for (int o = 0; o < 17; ++o) a += w[o] * win[(rr + o) % 17];
        float v = selu_f(a * sdinv_s[r0w + 16 + rr]);
        if (mode == 0) H[(size_t)(m0 + r0w + rr) * DIM + n0 + col] = f2bf(v);
        else psum += v;
    }
    if (mode == 0) return;

    // ---- mode 1: mean-pool + fused FC head ----------------------------------
    pl[t >> 7][col] = psum;
    __syncthreads();
    if (t < 128) atomicAdd(&pooled[n0 + t], pl[0][t] + pl[1][t]);
    __threadfence();
    __syncthreads();
    if (t == 0) ticket_s = atomicAdd(&cnt[0], 1u);
    __syncthreads();
    u32 ticket = ticket_s;
    if (ticket < 512 - 16) return;                // 16 elected blocks run the FC head
    if (t == 0) {
        while (__hip_atomic_load(&cnt[0], __ATOMIC_ACQUIRE, __HIP_MEMORY_SCOPE_AGENT) < 512u)
            __builtin_amdgcn_s_sleep(2);
    }
    __syncthreads();
    __threadfence();
    // fc1: k-slice of 64 pooled rows -> 512 outputs (2 per thread)
    int kb = (int)(ticket - (512 - 16)) * 64;
    if (t < 64)
        pl[0][t] = __hip_atomic_load(&pooled[kb + t], __ATOMIC_RELAXED,
                                     __HIP_MEMORY_SCOPE_AGENT) * (1.f / NND);
    __syncthreads();
    float a0 = 0.f, a1 = 0.f;
    #pragma unroll 8
    for (int kk = 0; kk < 64; ++kk) {
        float pv = pl[0][kk];
        const float* wrow = fcw1 + (size_t)(kb + kk) * FC1N + t;
        a0 += pv * wrow[0];
        a1 += pv * wrow[256];
    }
    atomicAdd(&zacc[t], a0);
    atomicAdd(&zacc[t + 256], a1);
    __threadfence();
    __syncthreads();
    if (t == 0) ticket_s = atomicAdd(&cnt[1], 1u);
    __syncthreads();
    if (ticket_s != 15) return;                   // only the last fc1 block continues
    __threadfence();
    float r0p = 0.f, r1p = 0.f;
    #pragma unroll
    for (int i = 0; i < 2; ++i) {
        int o = t + i * 256;
        float zv = __hip_atomic_load(&zacc[o], __ATOMIC_RELAXED, __HIP_MEMORY_SCOPE_AGENT);
        float z = selu_f(zv + fcb1[o]);
        r0p += z * fcw2[o * 2 + 0];
        r1p += z * fcw2[o * 2 + 1];
    }
    float* red = (float*)&stage[1][0];
    red[t] = r0p; red[256 + t] = r1p;
    __syncthreads();
    #pragma unroll 1
    for (int s2 = 128; s2 > 0; s2 >>= 1) {
        if (t < s2) { red[t] += red[t + s2]; red[256 + t] += red[256 + t + s2]; }
        __syncthreads();
    }
    if (t == 0) { out[0] = red[0] + fcb2[0]; out[1] = red[1] + fcb2[1]; }
}

extern "C" void kernel_launch(void* const* d_in, const int* in_sizes, int n_in,
                              void* d_out, int out_size, void* d_ws, size_t ws_size,
                              hipStream_t stream) {
    const float* x     = (const float*)d_in[0];
    const float* fw    = (const float*)d_in[1];
    const float* bw    = (const float*)d_in[2];
    const float* gc_w1 = (const float*)d_in[3];
    const float* gc_b1 = (const float*)d_in[4];
    const float* gc_w2 = (const float*)d_in[5];
    const float* gc_b2 = (const float*)d_in[6];
    const float* fc_w1 = (const float*)d_in[7];
    const float* fc_b1 = (const float*)d_in[8];
    const float* fc_w2 = (const float*)d_in[9];
    const float* fc_b2 = (const float*)d_in[10];
    float* out = (float*)d_out;

    char* ws = (char*)d_ws;
    u16*   Xb     = (u16*)(ws);                       // 8 MB
    u16*   H1     = (u16*)(ws + (8u  << 20));         // 8 MB
    u16*   W1t    = (u16*)(ws + (16u << 20));         // 2 MB
    u16*   W2t    = (u16*)(ws + (18u << 20));         // 2 MB
    float* pooled = (float*)(ws + (20u << 20));       // 1024 f
    float* zacc   = pooled + 1024;                    // 512 f
    u32*   cnt    = (u32*)(zacc + 512);               // 2 u32 (zeroed in prep)

    k_prep<<<1024, 256, 0, stream>>>(x, gc_w1, gc_w2, Xb, W1t, W2t, pooled);
    k_gemmband<<<dim3(64, 8), 256, 0, stream>>>(Xb, W1t, gc_b1, fw, bw, H1, nullptr,
                                                nullptr, nullptr, nullptr, nullptr,
                                                nullptr, nullptr, nullptr, 0);
    k_gemmband<<<dim3(64, 8), 256, 0, stream>>>(H1, W2t, gc_b2, fw, bw, nullptr, pooled,
                                                fc_w1, fc_b1, fc_w2, fc_b2,
                                                zacc, cnt, out, 1);
}